// Round 11
// baseline (362.256 us; speedup 1.0000x reference)
//
#include <hip/hip_runtime.h>

#define NB 16          // batch
#define NT 128         // boxes
#define NC 256         // channels

// sizes per level
#define S0 80
#define S1 40
#define S2 20

#define NM0 (NB*S0*S0)   // 102400 mask elems level0
#define NM1 (NB*S1*S1)   // 25600
#define NM2 (NB*S2*S2)   // 6400
#define NMTOT (NM0+NM1+NM2) // 134400

// element counts per level (for defensive input-order check)
#define NE0 (NB*NC*S0*S0)    // 26,214,400
#define NE1 (NB*NC*S1*S1)    //  6,553,600
#define NE2 (NB*NC*S2*S2)    //  1,638,400

// vec4 counts for pred/true per level
#define NV0 (NE0/4)  // 6,553,600
#define NV1 (NE1/4)  // 1,638,400
#define NV2 (NE2/4)  //   409,600

// ws layout (floats): [0..2] sum_sq per level, [3..5] C*sum_M per level,
// [6] block-done counter, [7] pad, [8 ...] masks (level0, level1, level2)
#define WS_MASK_OFF 8
#define REDUCE_BLOCKS 2048

typedef float f32x4 __attribute__((ext_vector_type(4)));

__global__ void mask_kernel(const float* __restrict__ bboxes,
                            const int* __restrict__ batch_idx,
                            float* __restrict__ ws) {
    // zero the 6 accumulator slots + counter; safe: this kernel completes
    // before reduce_kernel (same stream) and no block atomics them here
    if (blockIdx.x == 0 && threadIdx.x < 8) ws[threadIdx.x] = 0.0f;

    __shared__ float bx[NT], by[NT], bw[NT], bh[NT];
    __shared__ int   bb[NT];
    for (int t = threadIdx.x; t < NT; t += blockDim.x) {
        bx[t] = bboxes[t*4+0];
        by[t] = bboxes[t*4+1];
        bw[t] = bboxes[t*4+2];
        bh[t] = bboxes[t*4+3];
        bb[t] = batch_idx[t];
    }
    __syncthreads();

    int gid = blockIdx.x * blockDim.x + threadIdx.x;   // grid exactly covers NMTOT
    int S, idx, maskoff;
    if (gid < NM0)          { S = S0; idx = gid;             maskoff = 0;       }
    else if (gid < NM0+NM1) { S = S1; idx = gid - NM0;       maskoff = NM0;     }
    else                    { S = S2; idx = gid - NM0 - NM1; maskoff = NM0+NM1; }

    int sq  = S * S;
    int b   = idx / sq;
    int pix = idx - b * sq;
    int y = pix / S;
    int x = pix - y * S;
    float fS = (float)S;
    float m = 0.0f;
    for (int t = 0; t < NT; ++t) {
        if (bb[t] != b) continue;
        int xc = (int)floorf(bx[t] * fS);
        int yc = (int)floorf(by[t] * fS);
        int w  = (int)floorf(bw[t] * fS);
        int h  = (int)floorf(bh[t] * fS);
        int xl = max(xc - w/2, 0);
        int yt = max(yc - h/2, 0);
        int xr = min(xc + w/2, S-1);
        int yd = min(yc + h/2, S-1);
        if (x >= xl && x <= xr && y >= yt && y <= yd) { m = 1.0f; break; }
    }
    ws[WS_MASK_OFF + maskoff + idx] = m;
}

template <int SQ4>
__device__ __forceinline__ void accum_one(const f32x4* __restrict__ p,
                                          const f32x4* __restrict__ t,
                                          const f32x4* __restrict__ m4,
                                          int i4, float& acc, float& msum) {
    int bc   = i4 / SQ4;            // (b*NC + c), magic-mul since SQ4 constexpr
    int pixv = i4 - bc * SQ4;
    int b    = bc >> 8;             // / NC
    f32x4 pv = __builtin_nontemporal_load(&p[i4]);
    f32x4 tv = __builtin_nontemporal_load(&t[i4]);
    f32x4 mv = m4[b * SQ4 + pixv];  // hot in L2 (537 KB total)
    f32x4 d  = (pv - tv) * mv;
    acc  += d.x*d.x + d.y*d.y + d.z*d.z + d.w*d.w;
    msum += mv.x + mv.y + mv.z + mv.w;   // Σ over (b,c,pix) = C·sum(M)
}

__global__ __launch_bounds__(256) void reduce_kernel(
        const f32x4* __restrict__ p0, const f32x4* __restrict__ t0,
        const f32x4* __restrict__ p1, const f32x4* __restrict__ t1,
        const f32x4* __restrict__ p2, const f32x4* __restrict__ t2,
        float* __restrict__ ws, float* __restrict__ out) {
    const f32x4* m0 = (const f32x4*)(ws + WS_MASK_OFF);
    const f32x4* m1 = (const f32x4*)(ws + WS_MASK_OFF + NM0);
    const f32x4* m2 = (const f32x4*)(ws + WS_MASK_OFF + NM0 + NM1);

    const int gtid   = blockIdx.x * blockDim.x + threadIdx.x;
    const int stride = gridDim.x * blockDim.x;

    float acc0 = 0.f, acc1 = 0.f, acc2 = 0.f;
    float ms0  = 0.f, ms1  = 0.f, ms2  = 0.f;

    #pragma unroll 4
    for (int v = gtid; v < NV0; v += stride)
        accum_one<S0*S0/4>(p0, t0, m0, v, acc0, ms0);

    #pragma unroll 2
    for (int v = gtid; v < NV1; v += stride)
        accum_one<S1*S1/4>(p1, t1, m1, v, acc1, ms1);

    for (int v = gtid; v < NV2; v += stride)
        accum_one<S2*S2/4>(p2, t2, m2, v, acc2, ms2);

    // wave reduce (64 lanes)
    #pragma unroll
    for (int off = 32; off > 0; off >>= 1) {
        acc0 += __shfl_down(acc0, off);
        acc1 += __shfl_down(acc1, off);
        acc2 += __shfl_down(acc2, off);
        ms0  += __shfl_down(ms0,  off);
        ms1  += __shfl_down(ms1,  off);
        ms2  += __shfl_down(ms2,  off);
    }
    __shared__ float sacc[6][4];
    int wid  = threadIdx.x >> 6;
    int lane = threadIdx.x & 63;
    if (lane == 0) {
        sacc[0][wid] = acc0;  sacc[1][wid] = acc1;  sacc[2][wid] = acc2;
        sacc[3][wid] = ms0;   sacc[4][wid] = ms1;   sacc[5][wid] = ms2;
    }
    __syncthreads();
    if (threadIdx.x < 6) {
        float s = sacc[threadIdx.x][0] + sacc[threadIdx.x][1]
                + sacc[threadIdx.x][2] + sacc[threadIdx.x][3];
        if (s != 0.f) atomicAdd(&ws[threadIdx.x], s);
    }

    // last-block-done finalize: barrier drains the atomics above (vmcnt(0)
    // before s_barrier), so every lane's RMW is performed at the coherent
    // point before thread 0 bumps the counter.
    __syncthreads();
    if (threadIdx.x == 0) {
        __threadfence();
        float old = atomicAdd(&ws[6], 1.0f);
        if (old == (float)(REDUCE_BLOCKS - 1)) {
            // device-scope atomic reads (per-XCD L2 not coherent; plain
            // loads could be stale) — G16
            float s0 = atomicAdd(&ws[0], 0.0f);
            float s1 = atomicAdd(&ws[1], 0.0f);
            float s2 = atomicAdd(&ws[2], 0.0f);
            float n0 = atomicAdd(&ws[3], 0.0f);
            float n1 = atomicAdd(&ws[4], 0.0f);
            float n2 = atomicAdd(&ws[5], 0.0f);
            out[0] = (s0 / n0 + s1 / n1 + s2 / n2) * (1.0f / 3.0f);
        }
    }
}

extern "C" void kernel_launch(void* const* d_in, const int* in_sizes, int n_in,
                              void* d_out, int out_size, void* d_ws, size_t ws_size,
                              hipStream_t stream) {
    // setup_inputs() dict order is INTERLEAVED: pred0,true0,pred1,true1,
    // pred2,true2,bboxes,batch_idx,cls (the loop inserts pred{i} then
    // true{i}). Defensive: if in_sizes[1] matches level-1 size instead,
    // fall back to planar order.
    const void *pp0, *tt0, *pp1, *tt1, *pp2, *tt2;
    if (in_sizes[1] == NE0) {           // interleaved (expected)
        pp0 = d_in[0]; tt0 = d_in[1];
        pp1 = d_in[2]; tt1 = d_in[3];
        pp2 = d_in[4]; tt2 = d_in[5];
    } else {                            // planar fallback
        pp0 = d_in[0]; pp1 = d_in[1]; pp2 = d_in[2];
        tt0 = d_in[3]; tt1 = d_in[4]; tt2 = d_in[5];
    }
    const f32x4* p0 = (const f32x4*)pp0;
    const f32x4* t0 = (const f32x4*)tt0;
    const f32x4* p1 = (const f32x4*)pp1;
    const f32x4* t1 = (const f32x4*)tt1;
    const f32x4* p2 = (const f32x4*)pp2;
    const f32x4* t2 = (const f32x4*)tt2;
    const float* bboxes    = (const float*)d_in[6];
    const int*   batch_idx = (const int*)d_in[7];
    // d_in[8] = cls, unused
    float* ws  = (float*)d_ws;
    float* out = (float*)d_out;

    mask_kernel<<<NMTOT / 256, 256, 0, stream>>>(bboxes, batch_idx, ws);
    reduce_kernel<<<REDUCE_BLOCKS, 256, 0, stream>>>(p0, t0, p1, t1, p2, t2, ws, out);
}